// Round 1
// baseline (305.195 us; speedup 1.0000x reference)
//
#include <hip/hip_runtime.h>
#include <hip/hip_bf16.h>

typedef __bf16 bf16_t;
typedef __bf16 bf16x8 __attribute__((ext_vector_type(8)));
typedef float f32x4 __attribute__((ext_vector_type(4)));

#define T_SEQ 1024
#define BATCH 8
#define NH 8
#define DH 128
#define HKDIM 1024  // NH*DH

static __device__ __forceinline__ f32x4 mfma16(bf16x8 a, bf16x8 b, f32x4 c) {
    return __builtin_amdgcn_mfma_f32_16x16x32_bf16(a, b, c, 0, 0, 0);
}

// ---------------------------------------------------------------------------
// Kernel 1: convert inputs to bf16 working layouts.
//   xb[b][t][d]  = bf16(x[t][b][d])
//   w3[p][o][c]  = bf16(W_p[o][c])   p in {k,q,v}
//   wo[n][c]     = bf16(Wo[n][c])
// ---------------------------------------------------------------------------
__global__ void convert_kernel(const float* __restrict__ x,
                               const float* __restrict__ Wk,
                               const float* __restrict__ Wq,
                               const float* __restrict__ Wv,
                               const float* __restrict__ Wo,
                               bf16_t* __restrict__ xb,
                               bf16_t* __restrict__ w3,
                               bf16_t* __restrict__ wo) {
    const int stride = gridDim.x * blockDim.x;
    const int n1 = T_SEQ * BATCH * DH;        // 1048576
    const int n2 = n1 + 3 * HKDIM * DH;       // +393216
    const int n3 = n2 + DH * HKDIM;           // +131072
    for (int i = blockIdx.x * blockDim.x + threadIdx.x; i < n3; i += stride) {
        if (i < n1) {
            int d = i & 127;
            int t = (i >> 7) & 1023;
            int b = i >> 17;
            xb[i] = (bf16_t)x[(t * BATCH + b) * DH + d];
        } else if (i < n2) {
            int j = i - n1;
            int p = j >> 17;
            const float* W = (p == 0) ? Wk : (p == 1 ? Wq : Wv);
            w3[j] = (bf16_t)W[j & 131071];
        } else {
            int j = i - n2;
            wo[j] = (bf16_t)Wo[j];
        }
    }
}

// ---------------------------------------------------------------------------
// Kernel 2: QKV projection.  y[row, col] = sum_c xb[row, c] * w3[col, c] + bias
//   row = b*1024 + t (M=8192), col = p*1024 + h*128 + d (N=3072), K=128.
//   Output scattered to kbuf/qbuf/vbuf in [b][h][t][d] bf16.
// ---------------------------------------------------------------------------
__global__ __launch_bounds__(256) void proj_kernel(
        const bf16_t* __restrict__ xb, const bf16_t* __restrict__ w3,
        const float* __restrict__ bk, const float* __restrict__ bq,
        const float* __restrict__ bv,
        bf16_t* __restrict__ kbuf, bf16_t* __restrict__ qbuf,
        bf16_t* __restrict__ vbuf) {
    const int lane = threadIdx.x & 63;
    const int wave = threadIdx.x >> 6;
    const int lr = lane & 15, lq = lane >> 4;
    const int rm0 = blockIdx.x * 64 + wave * 16;
    const int cb0 = blockIdx.y * 64;

    bf16x8 aF[4];
#pragma unroll
    for (int kc = 0; kc < 4; ++kc)
        aF[kc] = *(const bf16x8*)(xb + (rm0 + lr) * DH + kc * 32 + lq * 8);

#pragma unroll
    for (int nc = 0; nc < 4; ++nc) {
        const int col0 = cb0 + nc * 16;
        f32x4 acc = {0.f, 0.f, 0.f, 0.f};
#pragma unroll
        for (int kc = 0; kc < 4; ++kc) {
            bf16x8 bF = *(const bf16x8*)(w3 + (col0 + lr) * DH + kc * 32 + lq * 8);
            acc = mfma16(aF[kc], bF, acc);
        }
        const int col = col0 + lr;
        const int p = col >> 10, within = col & 1023;
        const int h = within >> 7, d = within & 127;
        const float bias = (p == 0) ? bk[within] : (p == 1 ? bq[within] : bv[within]);
        bf16_t* dst = (p == 0) ? kbuf : (p == 1 ? qbuf : vbuf);
#pragma unroll
        for (int r = 0; r < 4; ++r) {
            const int row = rm0 + lq * 4 + r;
            const int bb = row >> 10, tt = row & 1023;
            dst[((size_t)(bb * NH + h) * T_SEQ + tt) * DH + d] = (bf16_t)(acc[r] + bias);
        }
    }
}

// ---------------------------------------------------------------------------
// Kernel 3: flash attention with swapped roles.
//   Q' := K_proj (rows i), K' := Q_proj (cols j), V := V_proj.
//   S[i,j] = Q'_i . K'_j * scale, mask j > i, softmax over j, O = P V.
//   Grid: (it=16, bh=64); 4 waves x 16 rows = 64-row i-tile; KV chunks of 32.
// ---------------------------------------------------------------------------
__global__ __launch_bounds__(256) void attn_kernel(
        const bf16_t* __restrict__ kbuf, const bf16_t* __restrict__ qbuf,
        const bf16_t* __restrict__ vbuf, bf16_t* __restrict__ obuf) {
    const int it = blockIdx.x, bh = blockIdx.y;
    const int b = bh >> 3, h = bh & 7;
    const int i0 = it * 64;
    const int lane = threadIdx.x & 63, wave = threadIdx.x >> 6;
    const int lr = lane & 15, lq = lane >> 4;

    const bf16_t* Qp = kbuf + (size_t)bh * T_SEQ * DH;  // role: query rows (key positions)
    const bf16_t* Kp = qbuf + (size_t)bh * T_SEQ * DH;  // role: keys (query positions)
    const bf16_t* Vp = vbuf + (size_t)bh * T_SEQ * DH;

    __shared__ __align__(16) bf16_t VtL[DH][40];      // V^T tile: [d][j], padded
    __shared__ __align__(16) bf16_t PL[4][16][40];    // per-wave P tile: [i][j], padded

    const int r0 = i0 + wave * 16;
    bf16x8 qf[4];
#pragma unroll
    for (int kc = 0; kc < 4; ++kc)
        qf[kc] = *(const bf16x8*)(Qp + (r0 + lr) * DH + kc * 32 + lq * 8);

    float mrow[4], lrow[4];
    f32x4 oacc[8];
#pragma unroll
    for (int r = 0; r < 4; ++r) { mrow[r] = -1e30f; lrow[r] = 0.f; }
#pragma unroll
    for (int n = 0; n < 8; ++n) oacc[n] = {0.f, 0.f, 0.f, 0.f};

    const float scale = 0.08838834764831845f;  // 1/sqrt(128)
    const int njc = 2 * it + 2;
    for (int jc = 0; jc < njc; ++jc) {
        const int j0 = jc * 32;
        __syncthreads();  // protect VtL from previous iteration's readers
        {
            // stage V^T: 32 rows x 128 cols -> VtL[d][j]
            const int c = threadIdx.x & 15, jl = threadIdx.x >> 4;
#pragma unroll
            for (int half = 0; half < 2; ++half) {
                const int jj = jl + half * 16;
                bf16x8 v8 = *(const bf16x8*)(Vp + (size_t)(j0 + jj) * DH + c * 8);
#pragma unroll
                for (int e = 0; e < 8; ++e) VtL[c * 8 + e][jj] = v8[e];
            }
        }
        __syncthreads();

        // S = Q' K'^T for two 16-wide column sub-chunks
        float sreg[2][4], cmax[4];
#pragma unroll
        for (int r = 0; r < 4; ++r) cmax[r] = -1e30f;
#pragma unroll
        for (int js = 0; js < 2; ++js) {
            const int jcol0 = j0 + js * 16;
            f32x4 sacc = {0.f, 0.f, 0.f, 0.f};
#pragma unroll
            for (int kc = 0; kc < 4; ++kc) {
                bf16x8 kf = *(const bf16x8*)(Kp + (size_t)(jcol0 + lr) * DH + kc * 32 + lq * 8);
                sacc = mfma16(qf[kc], kf, sacc);
            }
            const int col = jcol0 + lr;
#pragma unroll
            for (int r = 0; r < 4; ++r) {
                const int row = r0 + lq * 4 + r;
                float s = sacc[r] * scale;
                if (col > row) s = -1e30f;  // causal: mask j > i
                sreg[js][r] = s;
                cmax[r] = fmaxf(cmax[r], s);
            }
        }
        // row max across the 16 lanes holding this row's columns
#pragma unroll
        for (int off = 1; off < 16; off <<= 1)
#pragma unroll
            for (int r = 0; r < 4; ++r)
                cmax[r] = fmaxf(cmax[r], __shfl_xor(cmax[r], off, 64));

        // online softmax update
        float p[2][4], rs[4];
#pragma unroll
        for (int r = 0; r < 4; ++r) {
            const float mnew = fmaxf(mrow[r], cmax[r]);
            const float f = __expf(mrow[r] - mnew);
            mrow[r] = mnew;
            lrow[r] *= f;
#pragma unroll
            for (int n = 0; n < 8; ++n) oacc[n][r] *= f;
            const float p0 = __expf(sreg[0][r] - mnew);
            const float p1 = __expf(sreg[1][r] - mnew);
            p[0][r] = p0; p[1][r] = p1;
            rs[r] = p0 + p1;
        }
#pragma unroll
        for (int off = 1; off < 16; off <<= 1)
#pragma unroll
            for (int r = 0; r < 4; ++r)
                rs[r] += __shfl_xor(rs[r], off, 64);
#pragma unroll
        for (int r = 0; r < 4; ++r) lrow[r] += rs[r];

        // P -> LDS (per-wave), then PV via MFMA
#pragma unroll
        for (int js = 0; js < 2; ++js)
#pragma unroll
            for (int r = 0; r < 4; ++r)
                PL[wave][lq * 4 + r][js * 16 + lr] = (bf16_t)p[js][r];

        bf16x8 paf = *(const bf16x8*)(&PL[wave][lr][lq * 8]);
#pragma unroll
        for (int n = 0; n < 8; ++n) {
            bf16x8 vF = *(const bf16x8*)(&VtL[n * 16 + lr][lq * 8]);
            oacc[n] = mfma16(paf, vF, oacc[n]);
        }
    }

    // epilogue: normalize and store to obuf[b][t][h*128 + d]
#pragma unroll
    for (int r = 0; r < 4; ++r) {
        const float inv = 1.0f / lrow[r];
        const int row = r0 + lq * 4 + r;
#pragma unroll
        for (int n = 0; n < 8; ++n)
            obuf[((size_t)b * T_SEQ + row) * HKDIM + h * DH + n * 16 + lr] =
                (bf16_t)(oacc[n][r] * inv);
    }
}

// ---------------------------------------------------------------------------
// Kernel 4: output projection. out[t][b][n] = sum_c obuf[b][t][c]*Wo[n][c] + bo[n]
//   M=8192 (rows b*1024+t), N=128, K=1024. One block = 16 rows, 4 waves split N.
// ---------------------------------------------------------------------------
__global__ __launch_bounds__(256) void outproj_kernel(
        const bf16_t* __restrict__ obuf, const bf16_t* __restrict__ wo,
        const float* __restrict__ bo, float* __restrict__ out) {
    const int lane = threadIdx.x & 63, wave = threadIdx.x >> 6;
    const int lr = lane & 15, lq = lane >> 4;
    const int rm0 = blockIdx.x * 16;

    f32x4 acc[2] = {{0.f, 0.f, 0.f, 0.f}, {0.f, 0.f, 0.f, 0.f}};
    for (int kc = 0; kc < 32; ++kc) {
        bf16x8 aF = *(const bf16x8*)(obuf + (size_t)(rm0 + lr) * HKDIM + kc * 32 + lq * 8);
#pragma unroll
        for (int ni = 0; ni < 2; ++ni) {
            const int col0 = (wave * 2 + ni) * 16;
            bf16x8 bF = *(const bf16x8*)(wo + (size_t)(col0 + lr) * HKDIM + kc * 32 + lq * 8);
            acc[ni] = mfma16(aF, bF, acc[ni]);
        }
    }
#pragma unroll
    for (int ni = 0; ni < 2; ++ni) {
        const int col = (wave * 2 + ni) * 16 + lr;
        const float bias = bo[col];
#pragma unroll
        for (int r = 0; r < 4; ++r) {
            const int row = rm0 + lq * 4 + r;
            const int bb = row >> 10, tt = row & 1023;
            out[((size_t)tt * BATCH + bb) * DH + col] = acc[ni][r] + bias;
        }
    }
}

// ---------------------------------------------------------------------------
extern "C" void kernel_launch(void* const* d_in, const int* in_sizes, int n_in,
                              void* d_out, int out_size, void* d_ws, size_t ws_size,
                              hipStream_t stream) {
    const float* x  = (const float*)d_in[0];
    const float* Wk = (const float*)d_in[1];
    const float* bk = (const float*)d_in[2];
    const float* Wq = (const float*)d_in[3];
    const float* bq = (const float*)d_in[4];
    const float* Wv = (const float*)d_in[5];
    const float* bv = (const float*)d_in[6];
    const float* Wo = (const float*)d_in[7];
    const float* bo = (const float*)d_in[8];
    float* out = (float*)d_out;

    char* ws = (char*)d_ws;
    size_t off = 0;
    bf16_t* xb = (bf16_t*)(ws + off); off += (size_t)BATCH * T_SEQ * DH * 2;       // 2 MiB
    bf16_t* w3 = (bf16_t*)(ws + off); off += (size_t)3 * HKDIM * DH * 2;           // 0.75 MiB
    bf16_t* wo = (bf16_t*)(ws + off); off += (size_t)DH * HKDIM * 2;               // 0.25 MiB
    bf16_t* kb = (bf16_t*)(ws + off); off += (size_t)BATCH * NH * T_SEQ * DH * 2;  // 16 MiB
    bf16_t* qb = (bf16_t*)(ws + off); off += (size_t)BATCH * NH * T_SEQ * DH * 2;  // 16 MiB
    bf16_t* vb = (bf16_t*)(ws + off); off += (size_t)BATCH * NH * T_SEQ * DH * 2;  // 16 MiB
    bf16_t* ob = (bf16_t*)(ws + off); off += (size_t)BATCH * T_SEQ * HKDIM * 2;    // 16 MiB

    convert_kernel<<<1024, 256, 0, stream>>>(x, Wk, Wq, Wv, Wo, xb, w3, wo);
    proj_kernel<<<dim3(128, 48), 256, 0, stream>>>(xb, w3, bk, bq, bv, kb, qb, vb);
    attn_kernel<<<dim3(16, 64), 256, 0, stream>>>(kb, qb, vb, ob);
    outproj_kernel<<<512, 256, 0, stream>>>(ob, wo, bo, out);
}

// Round 2
// 229.651 us; speedup vs baseline: 1.3290x; 1.3290x over previous
//
#include <hip/hip_runtime.h>
#include <hip/hip_bf16.h>

typedef __bf16 bf16_t;
typedef __bf16 bf16x8 __attribute__((ext_vector_type(8)));
typedef __bf16 bf16x2_t __attribute__((ext_vector_type(2)));
typedef float f32x4 __attribute__((ext_vector_type(4)));
typedef unsigned int u32x4 __attribute__((ext_vector_type(4)));

#define T_SEQ 1024
#define BATCH 8
#define NH 8
#define DH 128
#define HKDIM 1024  // NH*DH

static __device__ __forceinline__ f32x4 mfma16(bf16x8 a, bf16x8 b, f32x4 c) {
    return __builtin_amdgcn_mfma_f32_16x16x32_bf16(a, b, c, 0, 0, 0);
}

static __device__ __forceinline__ unsigned pk2(float a, float b) {
    bf16x2_t t;
    t[0] = (bf16_t)a;
    t[1] = (bf16_t)b;
    union { bf16x2_t v; unsigned u; } c;
    c.v = t;
    return c.u;
}

// ---------------------------------------------------------------------------
// Kernel 1: convert inputs to bf16 working layouts.
// ---------------------------------------------------------------------------
__global__ void convert_kernel(const float* __restrict__ x,
                               const float* __restrict__ Wk,
                               const float* __restrict__ Wq,
                               const float* __restrict__ Wv,
                               const float* __restrict__ Wo,
                               bf16_t* __restrict__ xb,
                               bf16_t* __restrict__ w3,
                               bf16_t* __restrict__ wo) {
    const int stride = gridDim.x * blockDim.x;
    const int n1 = T_SEQ * BATCH * DH;        // 1048576
    const int n2 = n1 + 3 * HKDIM * DH;       // +393216
    const int n3 = n2 + DH * HKDIM;           // +131072
    for (int i = blockIdx.x * blockDim.x + threadIdx.x; i < n3; i += stride) {
        if (i < n1) {
            int d = i & 127;
            int t = (i >> 7) & 1023;
            int b = i >> 17;
            xb[i] = (bf16_t)x[(t * BATCH + b) * DH + d];
        } else if (i < n2) {
            int j = i - n1;
            int p = j >> 17;
            const float* W = (p == 0) ? Wk : (p == 1 ? Wq : Wv);
            w3[j] = (bf16_t)W[j & 131071];
        } else {
            int j = i - n2;
            wo[j] = (bf16_t)Wo[j];
        }
    }
}

// ---------------------------------------------------------------------------
// Kernel 2: QKV projection (unchanged from r1).
// ---------------------------------------------------------------------------
__global__ __launch_bounds__(256) void proj_kernel(
        const bf16_t* __restrict__ xb, const bf16_t* __restrict__ w3,
        const float* __restrict__ bk, const float* __restrict__ bq,
        const float* __restrict__ bv,
        bf16_t* __restrict__ kbuf, bf16_t* __restrict__ qbuf,
        bf16_t* __restrict__ vbuf) {
    const int lane = threadIdx.x & 63;
    const int wave = threadIdx.x >> 6;
    const int lr = lane & 15, lq = lane >> 4;
    const int rm0 = blockIdx.x * 64 + wave * 16;
    const int cb0 = blockIdx.y * 64;

    bf16x8 aF[4];
#pragma unroll
    for (int kc = 0; kc < 4; ++kc)
        aF[kc] = *(const bf16x8*)(xb + (rm0 + lr) * DH + kc * 32 + lq * 8);

#pragma unroll
    for (int nc = 0; nc < 4; ++nc) {
        const int col0 = cb0 + nc * 16;
        f32x4 acc = {0.f, 0.f, 0.f, 0.f};
#pragma unroll
        for (int kc = 0; kc < 4; ++kc) {
            bf16x8 bF = *(const bf16x8*)(w3 + (col0 + lr) * DH + kc * 32 + lq * 8);
            acc = mfma16(aF[kc], bF, acc);
        }
        const int col = col0 + lr;
        const int p = col >> 10, within = col & 1023;
        const int h = within >> 7, d = within & 127;
        const float bias = (p == 0) ? bk[within] : (p == 1 ? bq[within] : bv[within]);
        bf16_t* dst = (p == 0) ? kbuf : (p == 1 ? qbuf : vbuf);
#pragma unroll
        for (int r = 0; r < 4; ++r) {
            const int row = rm0 + lq * 4 + r;
            const int bb = row >> 10, tt = row & 1023;
            dst[((size_t)(bb * NH + h) * T_SEQ + tt) * DH + d] = (bf16_t)(acc[r] + bias);
        }
    }
}

// ---------------------------------------------------------------------------
// Kernel 2b: V transpose.  vbuf[bh][t][d] -> vtb[bh][d][t].
//   Block: 64-t x 128-d tile via LDS (stride 130 elems: conflict-free-ish).
// ---------------------------------------------------------------------------
__global__ __launch_bounds__(256) void transpose_v_kernel(
        const bf16_t* __restrict__ vbuf, bf16_t* __restrict__ vtb) {
    __shared__ bf16_t L[64 * 130];
    const int t0 = blockIdx.x * 64;
    const int bh = blockIdx.y;
    const bf16_t* src = vbuf + (size_t)bh * T_SEQ * DH;
    bf16_t* dst = vtb + (size_t)bh * DH * T_SEQ;
    const int tid = threadIdx.x;
    const int row = tid & 63;
    const int dg0 = (tid >> 6) * 4;
#pragma unroll
    for (int g = 0; g < 4; ++g) {
        const int d0 = (dg0 + g) * 8;
        bf16x8 v = *(const bf16x8*)(src + (size_t)(t0 + row) * DH + d0);
        union { bf16x8 v8; unsigned u[4]; } cv;
        cv.v8 = v;
        unsigned* lp = (unsigned*)&L[row * 130 + d0];
        lp[0] = cv.u[0]; lp[1] = cv.u[1]; lp[2] = cv.u[2]; lp[3] = cv.u[3];
    }
    __syncthreads();
    const int d = tid >> 1, th = tid & 1;
    bf16_t tmp[32];
#pragma unroll
    for (int k = 0; k < 32; ++k) tmp[k] = L[(th * 32 + k) * 130 + d];
#pragma unroll
    for (int k2 = 0; k2 < 4; ++k2) {
        bf16x8 o;
#pragma unroll
        for (int e = 0; e < 8; ++e) o[e] = tmp[k2 * 8 + e];
        *(bf16x8*)(dst + (size_t)d * T_SEQ + t0 + th * 32 + k2 * 8) = o;
    }
}

// ---------------------------------------------------------------------------
// Kernel 3: flash attention, swapped-QK^T, zero LDS, operands from L2.
//   Roles: Q' := K_proj (rows i), K' := Q_proj (cols j), V := V_proj.
//   S^T[j,i] = mfma(K'[j], Q'[i]); lane (lr,lq) holds P[i=lr][j=lq*4+r (+16)].
//   PV A-frag assembled via 8 bpermute shuffles; B-frag read from vtb (V^T).
//   Grid: 2048 x 128thr; bx>>6 = reversed itile (heavy first), bx&63 = bh
//   (keeps each head's K/V on one XCD's L2).
// ---------------------------------------------------------------------------
__global__ __launch_bounds__(128) void attn_kernel(
        const bf16_t* __restrict__ kbuf, const bf16_t* __restrict__ qbuf,
        const bf16_t* __restrict__ vtb, bf16_t* __restrict__ obuf) {
    const int bx = blockIdx.x;
    const int itile = 31 - (bx >> 6);
    const int bh = bx & 63;
    const int b = bh >> 3, h = bh & 7;
    const int wave = threadIdx.x >> 6;
    const int lane = threadIdx.x & 63;
    const int lr = lane & 15, lq = lane >> 4;
    const int r0 = itile * 32 + wave * 16;

    const bf16_t* Qp = kbuf + (size_t)bh * T_SEQ * DH;   // role: rows i
    const bf16_t* Kp = qbuf + (size_t)bh * T_SEQ * DH;   // role: cols j
    const bf16_t* Vt = vtb + (size_t)bh * DH * T_SEQ;    // [d][t]

    bf16x8 qf[4];
#pragma unroll
    for (int kc = 0; kc < 4; ++kc)
        qf[kc] = *(const bf16x8*)(Qp + (size_t)(r0 + lr) * DH + kc * 32 + lq * 8);

    f32x4 oacc[8];
#pragma unroll
    for (int n = 0; n < 8; ++n) oacc[n] = {0.f, 0.f, 0.f, 0.f};
    float m = 0.f, l = 0.f;
    // scale * log2(e): softmax computed in base-2 (exact: 2^(s*log2e)=e^s)
    const float C = 0.08838834764831845f * 1.4426950408889634f;

    const int njc = (r0 >> 5) + 1;
    for (int jc = 0; jc < njc; ++jc) {
        const int j0 = jc * 32;
        const bool last = (jc == njc - 1);

        // ---- S^T = K' Q'^T (two 16-j halves), operands straight from L2
        const bf16_t* k0 = Kp + (size_t)(j0 + lr) * DH + lq * 8;
        f32x4 sa = {0.f, 0.f, 0.f, 0.f}, sb = {0.f, 0.f, 0.f, 0.f};
        {
            bf16x8 kf0 = *(const bf16x8*)(k0);
            bf16x8 kf1 = *(const bf16x8*)(k0 + 32);
            bf16x8 kf2 = *(const bf16x8*)(k0 + 64);
            bf16x8 kf3 = *(const bf16x8*)(k0 + 96);
            sa = mfma16(kf0, qf[0], sa);
            sa = mfma16(kf1, qf[1], sa);
            sa = mfma16(kf2, qf[2], sa);
            sa = mfma16(kf3, qf[3], sa);
        }
        {
            const bf16_t* k1 = k0 + 16 * DH;
            bf16x8 kf0 = *(const bf16x8*)(k1);
            bf16x8 kf1 = *(const bf16x8*)(k1 + 32);
            bf16x8 kf2 = *(const bf16x8*)(k1 + 64);
            bf16x8 kf3 = *(const bf16x8*)(k1 + 96);
            sb = mfma16(kf0, qf[0], sb);
            sb = mfma16(kf1, qf[1], sb);
            sb = mfma16(kf2, qf[2], sb);
            sb = mfma16(kf3, qf[3], sb);
        }

        float s1[4], s2[4];
#pragma unroll
        for (int r = 0; r < 4; ++r) { s1[r] = sa[r] * C; s2[r] = sb[r] * C; }
        if (last) {
            const int i = r0 + lr;
#pragma unroll
            for (int r = 0; r < 4; ++r) {
                if (j0 + lq * 4 + r > i)      s1[r] = -1e30f;
                if (j0 + 16 + lq * 4 + r > i) s2[r] = -1e30f;
            }
        }

        // ---- online softmax (T13 defer-rescale; m in log2 units)
        float pm = fmaxf(fmaxf(fmaxf(s1[0], s1[1]), fmaxf(s1[2], s1[3])),
                         fmaxf(fmaxf(s2[0], s2[1]), fmaxf(s2[2], s2[3])));
        pm = fmaxf(pm, __shfl_xor(pm, 16, 64));
        pm = fmaxf(pm, __shfl_xor(pm, 32, 64));
        if (!__all(pm <= m + 12.0f)) {
            const float mnew = fmaxf(m, pm);
            const float f = exp2f(m - mnew);
            m = mnew;
            l *= f;
            float fr[4];
#pragma unroll
            for (int r = 0; r < 4; ++r)
                fr[r] = __shfl(f, (lane & 48) + lq * 4 + r, 64);
            const f32x4 fv = {fr[0], fr[1], fr[2], fr[3]};
#pragma unroll
            for (int n = 0; n < 8; ++n) oacc[n] *= fv;
        }

        float p1[4], p2[4];
        float ls = 0.f;
#pragma unroll
        for (int r = 0; r < 4; ++r) {
            p1[r] = exp2f(s1[r] - m);
            p2[r] = exp2f(s2[r] - m);
            ls += p1[r] + p2[r];
        }
        l += ls;  // per-lane partial; cross-lq reduce deferred to epilogue

        // ---- pack P to bf16 pairs (along j), redistribute to A-fragment
        const unsigned u1a = pk2(p1[0], p1[1]), u1b = pk2(p1[2], p1[3]);
        const unsigned u2a = pk2(p2[0], p2[1]), u2b = pk2(p2[2], p2[3]);
        const int srcA = lr + ((lq & 1) << 5);
        const int srcB = srcA + 16;
        const unsigned g0 = (unsigned)__shfl((int)u1a, srcA, 64);
        const unsigned g1 = (unsigned)__shfl((int)u1b, srcA, 64);
        const unsigned g2 = (unsigned)__shfl((int)u1a, srcB, 64);
        const unsigned g3 = (unsigned)__shfl((int)u1b, srcB, 64);
        const unsigned h0 = (unsigned)__shfl((int)u2a, srcA, 64);
        const unsigned h1 = (unsigned)__shfl((int)u2b, srcA, 64);
        const unsigned h2 = (unsigned)__shfl((int)u2a, srcB, 64);
        const unsigned h3 = (unsigned)__shfl((int)u2b, srcB, 64);
        const bool hi = (lq >= 2);
        union { u32x4 u; bf16x8 v; } pc;
        pc.u[0] = hi ? h0 : g0;
        pc.u[1] = hi ? h1 : g1;
        pc.u[2] = hi ? h2 : g2;
        pc.u[3] = hi ? h3 : g3;
        const bf16x8 pa = pc.v;

        // ---- PV: B-fragments straight from V^T in L2
        const bf16_t* vp = Vt + (size_t)lr * T_SEQ + j0 + lq * 8;
#pragma unroll
        for (int n = 0; n < 8; ++n) {
            bf16x8 vF = *(const bf16x8*)(vp + (size_t)n * 16 * T_SEQ);
            oacc[n] = mfma16(pa, vF, oacc[n]);
        }
    }

    // ---- epilogue
    l += __shfl_xor(l, 16, 64);
    l += __shfl_xor(l, 32, 64);
    float lrow[4];
#pragma unroll
    for (int r = 0; r < 4; ++r)
        lrow[r] = __shfl(l, (lane & 48) + lq * 4 + r, 64);
#pragma unroll
    for (int r = 0; r < 4; ++r) {
        const float inv = 1.0f / lrow[r];
        const int row = r0 + lq * 4 + r;
#pragma unroll
        for (int n = 0; n < 8; ++n)
            obuf[((size_t)b * T_SEQ + row) * HKDIM + h * DH + n * 16 + lr] =
                (bf16_t)(oacc[n][r] * inv);
    }
}

// ---------------------------------------------------------------------------
// Kernel 4: output projection (unchanged from r1).
// ---------------------------------------------------------------------------
__global__ __launch_bounds__(256) void outproj_kernel(
        const bf16_t* __restrict__ obuf, const bf16_t* __restrict__ wo,
        const float* __restrict__ bo, float* __restrict__ out) {
    const int lane = threadIdx.x & 63, wave = threadIdx.x >> 6;
    const int lr = lane & 15, lq = lane >> 4;
    const int rm0 = blockIdx.x * 16;

    f32x4 acc[2] = {{0.f, 0.f, 0.f, 0.f}, {0.f, 0.f, 0.f, 0.f}};
    for (int kc = 0; kc < 32; ++kc) {
        bf16x8 aF = *(const bf16x8*)(obuf + (size_t)(rm0 + lr) * HKDIM + kc * 32 + lq * 8);
#pragma unroll
        for (int ni = 0; ni < 2; ++ni) {
            const int col0 = (wave * 2 + ni) * 16;
            bf16x8 bF = *(const bf16x8*)(wo + (size_t)(col0 + lr) * HKDIM + kc * 32 + lq * 8);
            acc[ni] = mfma16(aF, bF, acc[ni]);
        }
    }
#pragma unroll
    for (int ni = 0; ni < 2; ++ni) {
        const int col = (wave * 2 + ni) * 16 + lr;
        const float bias = bo[col];
#pragma unroll
        for (int r = 0; r < 4; ++r) {
            const int row = rm0 + lq * 4 + r;
            const int bb = row >> 10, tt = row & 1023;
            out[((size_t)tt * BATCH + bb) * DH + col] = acc[ni][r] + bias;
        }
    }
}

// ---------------------------------------------------------------------------
extern "C" void kernel_launch(void* const* d_in, const int* in_sizes, int n_in,
                              void* d_out, int out_size, void* d_ws, size_t ws_size,
                              hipStream_t stream) {
    const float* x  = (const float*)d_in[0];
    const float* Wk = (const float*)d_in[1];
    const float* bk = (const float*)d_in[2];
    const float* Wq = (const float*)d_in[3];
    const float* bq = (const float*)d_in[4];
    const float* Wv = (const float*)d_in[5];
    const float* bv = (const float*)d_in[6];
    const float* Wo = (const float*)d_in[7];
    const float* bo = (const float*)d_in[8];
    float* out = (float*)d_out;

    char* ws = (char*)d_ws;
    size_t off = 0;
    bf16_t* xb  = (bf16_t*)(ws + off); off += (size_t)BATCH * T_SEQ * DH * 2;       // 2 MiB
    bf16_t* w3  = (bf16_t*)(ws + off); off += (size_t)3 * HKDIM * DH * 2;           // 0.75 MiB
    bf16_t* wo  = (bf16_t*)(ws + off); off += (size_t)DH * HKDIM * 2;               // 0.25 MiB
    bf16_t* kb  = (bf16_t*)(ws + off); off += (size_t)BATCH * NH * T_SEQ * DH * 2;  // 16 MiB
    bf16_t* qb  = (bf16_t*)(ws + off); off += (size_t)BATCH * NH * T_SEQ * DH * 2;  // 16 MiB
    bf16_t* vb  = (bf16_t*)(ws + off); off += (size_t)BATCH * NH * T_SEQ * DH * 2;  // 16 MiB
    bf16_t* vtb = (bf16_t*)(ws + off); off += (size_t)BATCH * NH * T_SEQ * DH * 2;  // 16 MiB
    bf16_t* ob  = (bf16_t*)(ws + off); off += (size_t)BATCH * T_SEQ * HKDIM * 2;    // 16 MiB

    convert_kernel<<<1024, 256, 0, stream>>>(x, Wk, Wq, Wv, Wo, xb, w3, wo);
    proj_kernel<<<dim3(128, 48), 256, 0, stream>>>(xb, w3, bk, bq, bv, kb, qb, vb);
    transpose_v_kernel<<<dim3(16, 64), 256, 0, stream>>>(vb, vtb);
    attn_kernel<<<2048, 128, 0, stream>>>(kb, qb, vtb, ob);
    outproj_kernel<<<512, 256, 0, stream>>>(ob, wo, bo, out);
}

// Round 4
// 163.872 us; speedup vs baseline: 1.8624x; 1.4014x over previous
//
#include <hip/hip_runtime.h>
#include <hip/hip_bf16.h>

typedef __bf16 bf16_t;
typedef __bf16 bf16x2_t __attribute__((ext_vector_type(2)));
typedef __bf16 bf16x4_t __attribute__((ext_vector_type(4)));
typedef __bf16 bf16x8 __attribute__((ext_vector_type(8)));
typedef float f32x4 __attribute__((ext_vector_type(4)));
typedef float f32x16 __attribute__((ext_vector_type(16)));
typedef unsigned int u32x2 __attribute__((ext_vector_type(2)));

#define T_SEQ 1024
#define BATCH 8
#define NH 8
#define DH 128
#define HKDIM 1024  // NH*DH

static __device__ __forceinline__ f32x4 mfma16(bf16x8 a, bf16x8 b, f32x4 c) {
    return __builtin_amdgcn_mfma_f32_16x16x32_bf16(a, b, c, 0, 0, 0);
}
static __device__ __forceinline__ f32x16 mfma32(bf16x8 a, bf16x8 b, f32x16 c) {
    return __builtin_amdgcn_mfma_f32_32x32x16_bf16(a, b, c, 0, 0, 0);
}

static __device__ __forceinline__ unsigned pk2(float a, float b) {
    bf16x2_t t;
    t[0] = (bf16_t)a;
    t[1] = (bf16_t)b;
    union { bf16x2_t v; unsigned u; } c;
    c.v = t;
    return c.u;
}

// v_permlane32_swap via builtin: r[0] = {a.lo, b.lo}, r[1] = {a.hi, b.hi}
// (dst.lanes[32:63] <-> src.lanes[0:31]; results are separate SSA values.)
static __device__ __forceinline__ void plswap(unsigned& a, unsigned& b) {
    u32x2 r = __builtin_amdgcn_permlane32_swap(a, b, false, false);
    a = r[0];
    b = r[1];
}

// value of x from lane^32 (pure VALU, no DS)
static __device__ __forceinline__ float swap_partner(float x) {
    u32x2 r = __builtin_amdgcn_permlane32_swap(__float_as_uint(x),
                                               __float_as_uint(x), false, false);
    // r[0][i>=32] = x[i-32];  r[1][i<32] = x[i+32]
    return __uint_as_float((threadIdx.x & 32) ? r[0] : r[1]);
}

// ---------------------------------------------------------------------------
// Kernel 1: convert inputs to bf16 working layouts (float4-vectorized).
// ---------------------------------------------------------------------------
__global__ __launch_bounds__(256) void convert_kernel(
        const float* __restrict__ x,
        const float* __restrict__ Wk, const float* __restrict__ Wq,
        const float* __restrict__ Wv, const float* __restrict__ Wo,
        bf16_t* __restrict__ xb, bf16_t* __restrict__ w3,
        bf16_t* __restrict__ wo) {
    const int n1 = T_SEQ * BATCH * DH;        // 1048576
    const int n2 = n1 + 3 * HKDIM * DH;       // +393216
    const int n3 = n2 + DH * HKDIM;           // +131072
    const int i = (blockIdx.x * 256 + threadIdx.x) * 4;
    if (i >= n3) return;
    const float* src;
    bf16_t* dst;
    if (i < n1) {
        int d = i & 127, t = (i >> 7) & 1023, b = i >> 17;
        src = x + (t * BATCH + b) * DH + d;
        dst = xb + i;
    } else if (i < n2) {
        int j = i - n1;
        int p = j >> 17;
        const float* W = (p == 0) ? Wk : (p == 1 ? Wq : Wv);
        src = W + (j & 131071);
        dst = w3 + j;
    } else {
        int j = i - n2;
        src = Wo + j;
        dst = wo + j;
    }
    f32x4 v = *(const f32x4*)src;
    bf16x4_t o;
    o[0] = (bf16_t)v[0]; o[1] = (bf16_t)v[1];
    o[2] = (bf16_t)v[2]; o[3] = (bf16_t)v[3];
    *(bf16x4_t*)dst = o;
}

// ---------------------------------------------------------------------------
// Kernel 2: QKV projection. K/Q written [bh][t][d]; V written TRANSPOSED
//   [bh][d][t] (feeds attention's PV A-fragments directly).
// ---------------------------------------------------------------------------
__global__ __launch_bounds__(256) void proj_kernel(
        const bf16_t* __restrict__ xb, const bf16_t* __restrict__ w3,
        const float* __restrict__ bk, const float* __restrict__ bq,
        const float* __restrict__ bv,
        bf16_t* __restrict__ kbuf, bf16_t* __restrict__ qbuf,
        bf16_t* __restrict__ vtbuf) {
    const int lane = threadIdx.x & 63;
    const int wave = threadIdx.x >> 6;
    const int lr = lane & 15, lq = lane >> 4;
    const int rm0 = blockIdx.x * 64 + wave * 16;
    const int cb0 = blockIdx.y * 64;

    bf16x8 aF[4];
#pragma unroll
    for (int kc = 0; kc < 4; ++kc)
        aF[kc] = *(const bf16x8*)(xb + (rm0 + lr) * DH + kc * 32 + lq * 8);

#pragma unroll
    for (int nc = 0; nc < 4; ++nc) {
        const int col0 = cb0 + nc * 16;
        f32x4 acc = {0.f, 0.f, 0.f, 0.f};
#pragma unroll
        for (int kc = 0; kc < 4; ++kc) {
            bf16x8 bF = *(const bf16x8*)(w3 + (col0 + lr) * DH + kc * 32 + lq * 8);
            acc = mfma16(aF[kc], bF, acc);
        }
        const int col = col0 + lr;
        const int p = col >> 10, within = col & 1023;
        const int h = within >> 7, d = within & 127;
        const float bias = (p == 0) ? bk[within] : (p == 1 ? bq[within] : bv[within]);
        if (p == 2) {
            // V transposed: vtbuf[bh][d][t]
#pragma unroll
            for (int r = 0; r < 4; ++r) {
                const int row = rm0 + lq * 4 + r;
                const int bb = row >> 10, tt = row & 1023;
                vtbuf[((size_t)(bb * NH + h) * DH + d) * T_SEQ + tt] =
                    (bf16_t)(acc[r] + bias);
            }
        } else {
            bf16_t* dst = (p == 0) ? kbuf : qbuf;
#pragma unroll
            for (int r = 0; r < 4; ++r) {
                const int row = rm0 + lq * 4 + r;
                const int bb = row >> 10, tt = row & 1023;
                dst[((size_t)(bb * NH + h) * T_SEQ + tt) * DH + d] =
                    (bf16_t)(acc[r] + bias);
            }
        }
    }
}

// ---------------------------------------------------------------------------
// Kernel 3: flash attention, 32x32 MFMA, in-lane softmax, permlane P-shuffle.
//   Roles: Q' := K_proj (rows i), K' := Q_proj (cols j), V := V_proj.
//   S^T = mfma32(K'[j], Q'[i]) -> lane holds half the j-rows for i = lane&31.
//   Block = 128 thr = 2 waves = 2 j-segments of one 32-row i-tile; merged
//   via LDS at the end. Zero DS ops / barriers in the main loop.
//   Grid: 2048; bx>>6 = reversed itile (heavy first), bx&63 = bh.
// ---------------------------------------------------------------------------
__global__ __launch_bounds__(128, 2) void attn_kernel(
        const bf16_t* __restrict__ kbuf, const bf16_t* __restrict__ qbuf,
        const bf16_t* __restrict__ vtb, bf16_t* __restrict__ obuf) {
    const int bx = blockIdx.x;
    const int itile = 31 - (bx >> 6);
    const int bh = bx & 63;
    const int b = bh >> 3, h = bh & 7;
    const int jseg = threadIdx.x >> 6;
    const int lane = threadIdx.x & 63;
    const int li = lane & 31;
    const int hi = lane >> 5;
    const int i0 = itile * 32;

    const bf16_t* Qp = kbuf + (size_t)bh * T_SEQ * DH;  // rows i (key positions)
    const bf16_t* Kp = qbuf + (size_t)bh * T_SEQ * DH;  // cols j (query positions)
    const bf16_t* Vt = vtb + (size_t)bh * DH * T_SEQ;   // [d][t]

    __shared__ float oL[128][32];   // [d][i] partial from jseg=1 (conflict-free)
    __shared__ float mlL[2][32];

    // persistent Q B-fragments: B[k=d][n=i], lane: i=li, k = s*16 + hi*8 + e
    bf16x8 qf[8];
#pragma unroll
    for (int s = 0; s < 8; ++s)
        qf[s] = *(const bf16x8*)(Qp + (size_t)(i0 + li) * DH + s * 16 + hi * 8);

    f32x16 oacc[4];
#pragma unroll
    for (int c = 0; c < 4; ++c)
#pragma unroll
        for (int e = 0; e < 16; ++e) oacc[c][e] = 0.f;

    float m = 0.f, l = 0.f;
    const float C = 0.08838834764831845f * 1.4426950408889634f;  // scale*log2e

    int jc = jseg;
    const bf16_t* kptr = Kp + (size_t)(jc * 32 + li) * DH + hi * 8;
    const bf16_t* vp0 = Vt + (size_t)li * T_SEQ + jc * 32 + hi * 8;
    const bf16_t* vp1 = vp0 + (size_t)32 * T_SEQ;
    const bf16_t* vp2 = vp0 + (size_t)64 * T_SEQ;
    const bf16_t* vp3 = vp0 + (size_t)96 * T_SEQ;

    // K A-fragments for first chunk: A[m=j][k=d], lane: j=j0+li
    bf16x8 ka[8];
    if (jc <= itile) {
#pragma unroll
        for (int s = 0; s < 8; ++s) ka[s] = *(const bf16x8*)(kptr + s * 16);
    }

    for (; jc <= itile; jc += 2) {
        // V A-fragments (issued early; latency hides under QK MFMAs)
        bf16x8 va[8];
        va[0] = *(const bf16x8*)(vp0);
        va[1] = *(const bf16x8*)(vp0 + 16);
        va[2] = *(const bf16x8*)(vp1);
        va[3] = *(const bf16x8*)(vp1 + 16);
        va[4] = *(const bf16x8*)(vp2);
        va[5] = *(const bf16x8*)(vp2 + 16);
        va[6] = *(const bf16x8*)(vp3);
        va[7] = *(const bf16x8*)(vp3 + 16);

        // S^T = K' Q'^T : C[m=j][n=i]
        f32x16 sc;
#pragma unroll
        for (int e = 0; e < 16; ++e) sc[e] = 0.f;
#pragma unroll
        for (int s = 0; s < 8; ++s) sc = mfma32(ka[s], qf[s], sc);

        // prefetch next K chunk (overlaps softmax + PV)
        kptr += (size_t)64 * DH;
        if (jc + 2 <= itile) {
#pragma unroll
            for (int s = 0; s < 8; ++s) ka[s] = *(const bf16x8*)(kptr + s * 16);
        }

        // scale (+ diagonal causal mask: j > i)
        f32x16 sv;
#pragma unroll
        for (int e = 0; e < 16; ++e) sv[e] = sc[e] * C;
        if (jc == itile) {
#pragma unroll
            for (int r = 0; r < 16; ++r) {
                const int jrow = (r & 3) + 8 * (r >> 2) + 4 * hi;
                if (jrow > li) sv[r] = -1e30f;
            }
        }

        // row max: in-lane tree + cross-half permlane (no DS)
        float pm = sv[0];
#pragma unroll
        for (int r = 1; r < 16; ++r) pm = fmaxf(pm, sv[r]);
        pm = fmaxf(pm, swap_partner(pm));

        // T13 defer-rescale (log2 domain, THR=8)
        if (!__all(pm <= m + 8.f)) {
            const float mn = fmaxf(m, pm);
            const float f = exp2f(m - mn);
            m = mn;
            l *= f;
#pragma unroll
            for (int c = 0; c < 4; ++c)
#pragma unroll
                for (int e = 0; e < 16; ++e) oacc[c][e] *= f;
        }

        // P = 2^(sv - m), pack to bf16 pairs along j
        float ls = 0.f;
        unsigned Wp[8];
#pragma unroll
        for (int q = 0; q < 4; ++q) {
            const float p0 = exp2f(sv[4 * q + 0] - m);
            const float p1 = exp2f(sv[4 * q + 1] - m);
            const float p2 = exp2f(sv[4 * q + 2] - m);
            const float p3 = exp2f(sv[4 * q + 3] - m);
            ls += (p0 + p1) + (p2 + p3);
            Wp[2 * q] = pk2(p0, p1);
            Wp[2 * q + 1] = pk2(p2, p3);
        }
        l += ls;

        // redistribute P into B-fragments: 4 permlane32_swap (pure VALU)
        plswap(Wp[0], Wp[2]);
        plswap(Wp[1], Wp[3]);
        plswap(Wp[4], Wp[6]);
        plswap(Wp[5], Wp[7]);
        union { unsigned u[4]; bf16x8 v; } pb0, pb1;
        pb0.u[0] = Wp[0]; pb0.u[1] = Wp[1]; pb0.u[2] = Wp[2]; pb0.u[3] = Wp[3];
        pb1.u[0] = Wp[4]; pb1.u[1] = Wp[5]; pb1.u[2] = Wp[6]; pb1.u[3] = Wp[7];

        // PV: O^T[d][i] += V^T[d][j] P[j][i]
        oacc[0] = mfma32(va[0], pb0.v, oacc[0]);
        oacc[0] = mfma32(va[1], pb1.v, oacc[0]);
        oacc[1] = mfma32(va[2], pb0.v, oacc[1]);
        oacc[1] = mfma32(va[3], pb1.v, oacc[1]);
        oacc[2] = mfma32(va[4], pb0.v, oacc[2]);
        oacc[2] = mfma32(va[5], pb1.v, oacc[2]);
        oacc[3] = mfma32(va[6], pb0.v, oacc[3]);
        oacc[3] = mfma32(va[7], pb1.v, oacc[3]);

        vp0 += 64; vp1 += 64; vp2 += 64; vp3 += 64;
    }

    const float lfull = l + swap_partner(l);

    // merge the two j-segments via LDS
    if (jseg == 1) {
        if (lane < 32) { mlL[0][li] = m; mlL[1][li] = lfull; }
#pragma unroll
        for (int c = 0; c < 4; ++c)
#pragma unroll
            for (int r = 0; r < 16; ++r) {
                const int d = c * 32 + (r & 3) + 8 * (r >> 2) + 4 * hi;
                oL[d][li] = oacc[c][r];
            }
    }
    __syncthreads();
    if (jseg == 0) {
        const float m1 = mlL[0][li], l1 = mlL[1][li];
        const float mx = fmaxf(m, m1);
        const float fa = exp2f(m - mx), fb = exp2f(m1 - mx);
        const float inv = 1.f / (lfull * fa + l1 * fb);
        bf16_t* orow = obuf + ((size_t)b * T_SEQ + i0 + li) * HKDIM + h * DH;
#pragma unroll
        for (int c = 0; c < 4; ++c)
#pragma unroll
            for (int q = 0; q < 4; ++q) {
                bf16x4_t o4;
#pragma unroll
                for (int rr = 0; rr < 4; ++rr) {
                    const int d = c * 32 + q * 8 + 4 * hi + rr;
                    o4[rr] = (bf16_t)((oacc[c][4 * q + rr] * fa + oL[d][li] * fb) * inv);
                }
                *(bf16x4_t*)(orow + c * 32 + q * 8 + 4 * hi) = o4;
            }
    }
}

// ---------------------------------------------------------------------------
// Kernel 4: output projection. out[t][b][n] = sum_c ob[b][t][c]*Wo[n][c]+bo[n]
// ---------------------------------------------------------------------------
__global__ __launch_bounds__(256) void outproj_kernel(
        const bf16_t* __restrict__ obuf, const bf16_t* __restrict__ wo,
        const float* __restrict__ bo, float* __restrict__ out) {
    const int lane = threadIdx.x & 63, wave = threadIdx.x >> 6;
    const int lr = lane & 15, lq = lane >> 4;
    const int rm0 = blockIdx.x * 16;

    f32x4 acc[2] = {{0.f, 0.f, 0.f, 0.f}, {0.f, 0.f, 0.f, 0.f}};
    for (int kc = 0; kc < 32; ++kc) {
        bf16x8 aF = *(const bf16x8*)(obuf + (size_t)(rm0 + lr) * HKDIM + kc * 32 + lq * 8);
#pragma unroll
        for (int ni = 0; ni < 2; ++ni) {
            const int col0 = (wave * 2 + ni) * 16;
            bf16x8 bF = *(const bf16x8*)(wo + (size_t)(col0 + lr) * HKDIM + kc * 32 + lq * 8);
            acc[ni] = mfma16(aF, bF, acc[ni]);
        }
    }
#pragma unroll
    for (int ni = 0; ni < 2; ++ni) {
        const int col = (wave * 2 + ni) * 16 + lr;
        const float bias = bo[col];
#pragma unroll
        for (int r = 0; r < 4; ++r) {
            const int row = rm0 + lq * 4 + r;
            const int bb = row >> 10, tt = row & 1023;
            out[((size_t)tt * BATCH + bb) * DH + col] = acc[ni][r] + bias;
        }
    }
}

// ---------------------------------------------------------------------------
extern "C" void kernel_launch(void* const* d_in, const int* in_sizes, int n_in,
                              void* d_out, int out_size, void* d_ws, size_t ws_size,
                              hipStream_t stream) {
    const float* x  = (const float*)d_in[0];
    const float* Wk = (const float*)d_in[1];
    const float* bk = (const float*)d_in[2];
    const float* Wq = (const float*)d_in[3];
    const float* bq = (const float*)d_in[4];
    const float* Wv = (const float*)d_in[5];
    const float* bv = (const float*)d_in[6];
    const float* Wo = (const float*)d_in[7];
    const float* bo = (const float*)d_in[8];
    float* out = (float*)d_out;

    char* ws = (char*)d_ws;
    size_t off = 0;
    bf16_t* xb  = (bf16_t*)(ws + off); off += (size_t)BATCH * T_SEQ * DH * 2;       // 2 MiB
    bf16_t* w3  = (bf16_t*)(ws + off); off += (size_t)3 * HKDIM * DH * 2;           // 0.75 MiB
    bf16_t* wo  = (bf16_t*)(ws + off); off += (size_t)DH * HKDIM * 2;               // 0.25 MiB
    bf16_t* kb  = (bf16_t*)(ws + off); off += (size_t)BATCH * NH * T_SEQ * DH * 2;  // 16 MiB
    bf16_t* qb  = (bf16_t*)(ws + off); off += (size_t)BATCH * NH * T_SEQ * DH * 2;  // 16 MiB
    bf16_t* vtb = (bf16_t*)(ws + off); off += (size_t)BATCH * NH * T_SEQ * DH * 2;  // 16 MiB
    bf16_t* ob  = (bf16_t*)(ws + off); off += (size_t)BATCH * T_SEQ * HKDIM * 2;    // 16 MiB

    convert_kernel<<<1536, 256, 0, stream>>>(x, Wk, Wq, Wv, Wo, xb, w3, wo);
    proj_kernel<<<dim3(128, 48), 256, 0, stream>>>(xb, w3, bk, bq, bv, kb, qb, vtb);
    attn_kernel<<<2048, 128, 0, stream>>>(kb, qb, vtb, ob);
    outproj_kernel<<<512, 256, 0, stream>>>(ob, wo, bo, out);
}